// Round 6
// baseline (191.207 us; speedup 1.0000x reference)
//
#include <hip/hip_runtime.h>
#include <stdint.h>

typedef unsigned long long u64;
typedef unsigned int u32;

#define T_STEPS 64
#define KDIM 784
#define N1 1024
#define NB 2048
#define N2 10

// ---------------- K0: W2 [10][1024] -> W2T [1024][12] (padded rows) ----------------
__global__ void k_w2t(const float* __restrict__ W2, float* __restrict__ W2T) {
    int j = blockIdx.x * blockDim.x + threadIdx.x;
    if (j >= N1) return;
    float r[12];
#pragma unroll
    for (int i = 0; i < 10; ++i) r[i] = W2[i * N1 + j];
    r[10] = 0.f; r[11] = 0.f;
#pragma unroll
    for (int i = 0; i < 12; ++i) W2T[j * 12 + i] = r[i];
}

// ---------------- K0b: tiled transposes X->Xt [784][2048], W1->W1t [784][1024] ----------------
__global__ __launch_bounds__(256) void k_transpose2(
    const float* __restrict__ X, float* __restrict__ Xt,
    const float* __restrict__ W1, float* __restrict__ W1t)
{
    __shared__ float t[32][33];
    int b = blockIdx.x;
    const float* src; float* dst; int R;
    int tile_r, tile_c;
    if (b < 1600) { src = X;  dst = Xt;  R = NB; tile_r = b / 25; tile_c = b % 25; }
    else { b -= 1600; src = W1; dst = W1t; R = N1; tile_r = b / 25; tile_c = b % 25; }

    const int tx = threadIdx.x & 31, ty = threadIdx.x >> 5;
    const int r0 = tile_r << 5, c0 = tile_c << 5;

#pragma unroll
    for (int i = 0; i < 32; i += 8) {
        int c = c0 + tx;
        t[ty + i][tx] = (c < KDIM) ? src[(size_t)(r0 + ty + i) * KDIM + c] : 0.f;
    }
    __syncthreads();
#pragma unroll
    for (int i = 0; i < 32; i += 8) {
        int c = c0 + ty + i;
        if (c < KDIM) dst[(size_t)c * R + r0 + tx] = t[tx][ty + i];
    }
}

// ---------------- K1: c1 = X @ W1^T (fp32), glds dbuf, 512 threads, fused LIF-1 ----------------
// 64x64 block tile, 512 threads (8 waves -> 4 waves/SIMD at 2 blocks/CU), 2x4 per thread.
// Waves 0-3 stage the A tile via global_load_lds w16, waves 4-7 stage B.
// FMA order per accumulator: k ascending, strictly sequential -> c1 bit-identical.
#define NSTEP (KDIM / 16)   // 49

typedef const __attribute__((address_space(1))) void gas_void;
typedef __attribute__((address_space(3))) void las_void;

__global__ __launch_bounds__(512) void k_gemm_lif1(
    const float* __restrict__ Xt,    // [784][2048]
    const float* __restrict__ W1t,   // [784][1024]
    u64* __restrict__ bits)
{
    __shared__ __align__(16) float A2[2][16][64];   // 8 KB
    __shared__ __align__(16) float B2[2][16][64];   // 8 KB

    const int tid  = threadIdx.x;
    const int lane = tid & 63;
    const int tx   = tid & 15;             // n-group (4 cols)
    const int tyy  = tid >> 4;             // m-group (0..31, 2 rows each)
    const int bm   = blockIdx.y << 6;
    const int bn   = blockIdx.x << 6;

    // staging: waves 0-3 stage A rows, waves 4-7 stage B rows (4 rows/wave)
    const int stid = (tid < 256) ? tid : tid - 256;
    const int w4   = __builtin_amdgcn_readfirstlane((stid >> 6) << 2);
    const int srow = w4 + (lane >> 4);
    const int scol = (lane & 15) << 2;

    const float* gA = Xt  + (size_t)srow * NB + bm + scol;
    const float* gB = W1t + (size_t)srow * N1 + bn + scol;

#define STAGE(pp, t)                                                              \
    {                                                                             \
        if (tid < 256)                                                            \
            __builtin_amdgcn_global_load_lds((gas_void*)(gA + (size_t)(t) * (16 * NB)), \
                                             (las_void*)&A2[pp][w4][0], 16, 0, 0); \
        else                                                                      \
            __builtin_amdgcn_global_load_lds((gas_void*)(gB + (size_t)(t) * (16 * N1)), \
                                             (las_void*)&B2[pp][w4][0], 16, 0, 0); \
    }

    float acc[2][4];
#pragma unroll
    for (int r = 0; r < 2; ++r)
#pragma unroll
        for (int c = 0; c < 4; ++c) acc[r][c] = 0.f;

    // prologue
    STAGE(0, 0);
    asm volatile("s_waitcnt vmcnt(0)" ::: "memory");
    __builtin_amdgcn_s_barrier();
    __builtin_amdgcn_sched_barrier(0);

    int p = 0;
    for (int t = 0; t < NSTEP; ++t) {
        if (t + 1 < NSTEP) STAGE(p ^ 1, t + 1);
#pragma unroll
        for (int kk = 0; kk < 16; ++kk) {
            float2 av = *(const float2*)(&A2[p][kk][tyy << 1]);
            float4 bv = *(const float4*)(&B2[p][kk][tx << 2]);
            acc[0][0] = fmaf(av.x, bv.x, acc[0][0]); acc[0][1] = fmaf(av.x, bv.y, acc[0][1]);
            acc[0][2] = fmaf(av.x, bv.z, acc[0][2]); acc[0][3] = fmaf(av.x, bv.w, acc[0][3]);
            acc[1][0] = fmaf(av.y, bv.x, acc[1][0]); acc[1][1] = fmaf(av.y, bv.y, acc[1][1]);
            acc[1][2] = fmaf(av.y, bv.z, acc[1][2]); acc[1][3] = fmaf(av.y, bv.w, acc[1][3]);
        }
        asm volatile("s_waitcnt vmcnt(0)" ::: "memory");
        __builtin_amdgcn_s_barrier();
        __builtin_amdgcn_sched_barrier(0);
        p ^= 1;
    }
#undef STAGE

    // LIF layer 1: exact per-step recurrence, spikes recorded as 64-bit mask.
    float c[8], v[8];
    u32 blo[8], bhi[8];
#pragma unroll
    for (int u = 0; u < 8; ++u) {
        c[u] = acc[u >> 2][u & 3];
        v[u] = 0.f; blo[u] = 0u; bhi[u] = 0u;
    }
    for (int t = 0; t < 32; ++t) {
#pragma unroll
        for (int u = 0; u < 8; ++u) {
            v[u] += (c[u] - v[u]) * 0.5f;           // v += (c - v)/tau, tau=2
            bool s = v[u] >= 1.0f;                  // spike(v - 1) == (v >= 1)
            blo[u] |= (s ? 1u : 0u) << t;
            v[u] = s ? 0.f : v[u];                  // hard reset
        }
    }
    for (int t = 0; t < 32; ++t) {
#pragma unroll
        for (int u = 0; u < 8; ++u) {
            v[u] += (c[u] - v[u]) * 0.5f;
            bool s = v[u] >= 1.0f;
            bhi[u] |= (s ? 1u : 0u) << t;
            v[u] = s ? 0.f : v[u];
        }
    }
#pragma unroll
    for (int u = 0; u < 8; ++u) {
        int r = u >> 2, cc = u & 3;
        bits[(size_t)(bm + (tyy << 1) + r) * N1 + (bn + (tx << 2) + cc)] =
            ((u64)bhi[u] << 32) | (u64)blo[u];
    }
}

// ---------------- K3: sparse c2, 1 batch/block, 4 waves x 256-j segments ----------------
// Phase 2 unrolled x8 over a zero-padded compacted list (mask=0 entries are exact no-ops).
__global__ __launch_bounds__(256) void k_lif2(
    const u64* __restrict__ bits, const float* __restrict__ W2T,
    float* __restrict__ out)
{
    __shared__ u64  masksS[N1];         // 8 KB
    __shared__ u32  idxS[N1];           // 4 KB
    __shared__ float c2S[4][64][12];    // 12 KB (per-wave partials)
    __shared__ float s2S[64][10];       // 2.5 KB

    const int tid  = threadIdx.x;
    const int w    = tid >> 6;      // wave = j-segment
    const int lane = tid & 63;      // = timestep in phase 2
    const int b    = blockIdx.x;

    const u64* row = bits + (size_t)b * N1;
    const int base_j = w << 8;

    // ---- phase 1: each wave scans its 256-j segment, ballot-compacts ----
    int nact = 0;
#pragma unroll
    for (int it = 0; it < 4; ++it) {
        int j = base_j + (it << 6) + lane;
        u64 m = row[j];
        u64 ball = __ballot(m != 0ULL);
        int pos = nact + __popcll(ball & ((1ULL << lane) - 1ULL));
        if (m != 0ULL) { masksS[base_j + pos] = m; idxS[base_j + pos] = j; }
        nact += __popcll(ball);
    }
    // zero-pad to multiple of 8 (mask=0 -> sf=0 for all lanes -> exact no-op)
    const int npad = (nact + 7) & ~7;
    if (lane < npad - nact) { masksS[base_j + nact + lane] = 0ULL; idxS[base_j + nact + lane] = 0u; }

    // ---- phase 2: dense accumulation over active list; lane = t; unroll 8 ----
    float acc[10];
#pragma unroll
    for (int i = 0; i < 10; ++i) acc[i] = 0.f;

    for (int a = 0; a < npad; a += 8) {
        u64 m[8]; u32 j[8];
#pragma unroll
        for (int q = 0; q < 8; ++q) {
            m[q] = masksS[base_j + a + q];
            j[q] = idxS[base_j + a + q];
        }
#pragma unroll
        for (int q = 0; q < 8; ++q) {
            float sf = (float)((m[q] >> lane) & 1ULL);
            const float* wr = W2T + j[q] * 12;       // uniform vector addr -> L1 broadcast
            float4 w0 = *(const float4*)(wr);
            float4 w1 = *(const float4*)(wr + 4);
            float2 w2 = *(const float2*)(wr + 8);
            acc[0] = fmaf(sf, w0.x, acc[0]); acc[1] = fmaf(sf, w0.y, acc[1]);
            acc[2] = fmaf(sf, w0.z, acc[2]); acc[3] = fmaf(sf, w0.w, acc[3]);
            acc[4] = fmaf(sf, w1.x, acc[4]); acc[5] = fmaf(sf, w1.y, acc[5]);
            acc[6] = fmaf(sf, w1.z, acc[6]); acc[7] = fmaf(sf, w1.w, acc[7]);
            acc[8] = fmaf(sf, w2.x, acc[8]); acc[9] = fmaf(sf, w2.y, acc[9]);
        }
    }

#pragma unroll
    for (int i = 0; i < 10; ++i) c2S[w][lane][i] = acc[i];
    __syncthreads();

    // ---- reduce 4 partials + LIF layer 2 (10 threads, serial over t) ----
    if (tid < 10) {
        const int i = tid;
        float v2 = 0.f;
        for (int t = 0; t < 64; ++t) {
            float cc = ((c2S[0][t][i] + c2S[1][t][i]) + c2S[2][t][i]) + c2S[3][t][i];
            v2 += (cc - v2) * 0.5f;
            bool s = v2 >= 1.0f;
            s2S[t][i] = s ? 1.f : 0.f;
            v2 = s ? 0.f : v2;
        }
    }
    __syncthreads();

    // ---- write out[t][b][0..9] ----
    for (int idx = tid; idx < 64 * 10; idx += 256) {
        int t = idx / 10, i = idx % 10;
        out[(size_t)t * (NB * N2) + (size_t)b * N2 + i] = s2S[t][i];
    }
}

extern "C" void kernel_launch(void* const* d_in, const int* in_sizes, int n_in,
                              void* d_out, int out_size, void* d_ws, size_t ws_size,
                              hipStream_t stream) {
    const float* X  = (const float*)d_in[0];   // [2048, 784]
    const float* W1 = (const float*)d_in[1];   // [1024, 784]
    const float* W2 = (const float*)d_in[2];   // [10, 1024]
    float* out = (float*)d_out;                // [64, 2048, 10]

    char* ws = (char*)d_ws;
    u64*   bits = (u64*)ws;                                   // 16 MiB
    float* W2T  = (float*)(ws + (size_t)NB * N1 * 8);         // 48 KiB
    float* Xt   = (float*)(ws + (size_t)NB * N1 * 8 + 65536); // 6.27 MiB
    float* W1t  = Xt + (size_t)KDIM * NB;                     // 3.14 MiB

    k_w2t<<<dim3((N1 + 255) / 256), dim3(256), 0, stream>>>(W2, W2T);
    k_transpose2<<<dim3(2400), dim3(256), 0, stream>>>(X, Xt, W1, W1t);

    dim3 g1(N1 / 64, NB / 64);   // (16, 32)
    k_gemm_lif1<<<g1, dim3(512), 0, stream>>>(Xt, W1t, bits);

    k_lif2<<<dim3(NB), dim3(256), 0, stream>>>(bits, W2T, out);
}

// Round 7
// 180.060 us; speedup vs baseline: 1.0619x; 1.0619x over previous
//
#include <hip/hip_runtime.h>
#include <stdint.h>

typedef unsigned long long u64;
typedef unsigned int u32;

#define T_STEPS 64
#define KDIM 784
#define N1 1024
#define NB 2048
#define N2 10

// ---------------- K0: W2 [10][1024] -> W2T [1024][12] (padded rows) ----------------
__global__ void k_w2t(const float* __restrict__ W2, float* __restrict__ W2T) {
    int j = blockIdx.x * blockDim.x + threadIdx.x;
    if (j >= N1) return;
    float r[12];
#pragma unroll
    for (int i = 0; i < 10; ++i) r[i] = W2[i * N1 + j];
    r[10] = 0.f; r[11] = 0.f;
#pragma unroll
    for (int i = 0; i < 12; ++i) W2T[j * 12 + i] = r[i];
}

// ---------------- K0b: tiled transposes X->Xt [784][2048], W1->W1t [784][1024] ----------------
__global__ __launch_bounds__(256) void k_transpose2(
    const float* __restrict__ X, float* __restrict__ Xt,
    const float* __restrict__ W1, float* __restrict__ W1t)
{
    __shared__ float t[32][33];
    int b = blockIdx.x;
    const float* src; float* dst; int R;
    int tile_r, tile_c;
    if (b < 1600) { src = X;  dst = Xt;  R = NB; tile_r = b / 25; tile_c = b % 25; }
    else { b -= 1600; src = W1; dst = W1t; R = N1; tile_r = b / 25; tile_c = b % 25; }

    const int tx = threadIdx.x & 31, ty = threadIdx.x >> 5;
    const int r0 = tile_r << 5, c0 = tile_c << 5;

#pragma unroll
    for (int i = 0; i < 32; i += 8) {
        int c = c0 + tx;
        t[ty + i][tx] = (c < KDIM) ? src[(size_t)(r0 + ty + i) * KDIM + c] : 0.f;
    }
    __syncthreads();
#pragma unroll
    for (int i = 0; i < 32; i += 8) {
        int c = c0 + ty + i;
        if (c < KDIM) dst[(size_t)c * R + r0 + tx] = t[tx][ty + i];
    }
}

// ---------------- K1: c1 = X @ W1^T (fp32), 4-buffer counted-vmcnt pipeline, fused LIF-1 ----
// 64x64 tile, 256 threads, 4x4/thread. glds w16 staging, prefetch depth 2,
// s_waitcnt vmcnt(2) in steady state (stage t+1 stays in flight), vmcnt(0) only
// on the peeled final iteration. FMA order: k ascending sequential -> bit-identical.
#define NSTEP (KDIM / 16)   // 49

typedef const __attribute__((address_space(1))) void gas_void;
typedef __attribute__((address_space(3))) void las_void;

__global__ __launch_bounds__(256) void k_gemm_lif1(
    const float* __restrict__ Xt,    // [784][2048]
    const float* __restrict__ W1t,   // [784][1024]
    u64* __restrict__ bits)
{
    __shared__ __align__(16) float A2[4][16][64];   // 16 KB
    __shared__ __align__(16) float B2[4][16][64];   // 16 KB

    const int tid  = threadIdx.x;
    const int lane = tid & 63;
    const int tx   = tid & 15;             // n-group
    const int ty   = tid >> 4;             // m-group (0..15)
    const int bm   = blockIdx.y << 6;
    const int bn   = blockIdx.x << 6;

    // staging: wave w owns rows 4w..4w+3 of each 16x64 tile (A and B)
    const int w4   = __builtin_amdgcn_readfirstlane((tid >> 6) << 2);
    const int srow = w4 + (lane >> 4);
    const int scol = (lane & 15) << 2;

    const float* gA = Xt  + (size_t)srow * NB + bm + scol;
    const float* gB = W1t + (size_t)srow * N1 + bn + scol;

#define STAGE(pp, t)                                                          \
    {                                                                         \
        __builtin_amdgcn_global_load_lds((gas_void*)(gA + (size_t)(t) * (16 * NB)), \
                                         (las_void*)&A2[pp][w4][0], 16, 0, 0); \
        __builtin_amdgcn_global_load_lds((gas_void*)(gB + (size_t)(t) * (16 * N1)), \
                                         (las_void*)&B2[pp][w4][0], 16, 0, 0); \
    }

#define COMPUTE(cur)                                                          \
    _Pragma("unroll")                                                         \
    for (int kk = 0; kk < 16; ++kk) {                                         \
        float4 av = *(const float4*)(&A2[cur][kk][ty << 2]);                  \
        float4 bv = *(const float4*)(&B2[cur][kk][tx << 2]);                  \
        acc[0][0] = fmaf(av.x, bv.x, acc[0][0]); acc[0][1] = fmaf(av.x, bv.y, acc[0][1]); \
        acc[0][2] = fmaf(av.x, bv.z, acc[0][2]); acc[0][3] = fmaf(av.x, bv.w, acc[0][3]); \
        acc[1][0] = fmaf(av.y, bv.x, acc[1][0]); acc[1][1] = fmaf(av.y, bv.y, acc[1][1]); \
        acc[1][2] = fmaf(av.y, bv.z, acc[1][2]); acc[1][3] = fmaf(av.y, bv.w, acc[1][3]); \
        acc[2][0] = fmaf(av.z, bv.x, acc[2][0]); acc[2][1] = fmaf(av.z, bv.y, acc[2][1]); \
        acc[2][2] = fmaf(av.z, bv.z, acc[2][2]); acc[2][3] = fmaf(av.z, bv.w, acc[2][3]); \
        acc[3][0] = fmaf(av.w, bv.x, acc[3][0]); acc[3][1] = fmaf(av.w, bv.y, acc[3][1]); \
        acc[3][2] = fmaf(av.w, bv.z, acc[3][2]); acc[3][3] = fmaf(av.w, bv.w, acc[3][3]); \
    }

    float acc[4][4];
#pragma unroll
    for (int r = 0; r < 4; ++r)
#pragma unroll
        for (int c = 0; c < 4; ++c) acc[r][c] = 0.f;

    // prologue: 2 stages in flight
    STAGE(0, 0);
    STAGE(1, 1);

    for (int t = 0; t < NSTEP - 1; ++t) {
        // stage t complete once only the 2 newest ops (stage t+1) remain
        asm volatile("s_waitcnt vmcnt(2)" ::: "memory");
        __builtin_amdgcn_sched_barrier(0);
        __builtin_amdgcn_s_barrier();
        __builtin_amdgcn_sched_barrier(0);
        if (t + 2 < NSTEP) STAGE((t + 2) & 3, t + 2);
        __builtin_amdgcn_sched_barrier(0);
        const int cur = t & 3;
        COMPUTE(cur);
        __builtin_amdgcn_sched_barrier(0);
    }
    // peeled last iteration: must fully drain
    asm volatile("s_waitcnt vmcnt(0)" ::: "memory");
    __builtin_amdgcn_sched_barrier(0);
    __builtin_amdgcn_s_barrier();
    __builtin_amdgcn_sched_barrier(0);
    {
        const int cur = (NSTEP - 1) & 3;
        COMPUTE(cur);
    }
#undef STAGE
#undef COMPUTE

    // LIF layer 1: exact per-step recurrence, spikes recorded as 64-bit mask.
    float c[16], v[16];
    u32 blo[16], bhi[16];
#pragma unroll
    for (int u = 0; u < 16; ++u) {
        c[u] = acc[u >> 2][u & 3];
        v[u] = 0.f; blo[u] = 0u; bhi[u] = 0u;
    }
    for (int t = 0; t < 32; ++t) {
#pragma unroll
        for (int u = 0; u < 16; ++u) {
            v[u] += (c[u] - v[u]) * 0.5f;           // v += (c - v)/tau, tau=2
            bool s = v[u] >= 1.0f;                  // spike(v - 1) == (v >= 1)
            blo[u] |= (s ? 1u : 0u) << t;
            v[u] = s ? 0.f : v[u];                  // hard reset
        }
    }
    for (int t = 0; t < 32; ++t) {
#pragma unroll
        for (int u = 0; u < 16; ++u) {
            v[u] += (c[u] - v[u]) * 0.5f;
            bool s = v[u] >= 1.0f;
            bhi[u] |= (s ? 1u : 0u) << t;
            v[u] = s ? 0.f : v[u];
        }
    }
#pragma unroll
    for (int u = 0; u < 16; ++u) {
        int r = u >> 2, cc = u & 3;
        bits[(size_t)(bm + (ty << 2) + r) * N1 + (bn + (tx << 2) + cc)] =
            ((u64)bhi[u] << 32) | (u64)blo[u];
    }
}

// ---------------- K2: sparse c2 via compaction -> dense c2d[b][64][10] ----------------
// 1 batch/block, 4 waves x 256-j segments. No serial LIF tail here.
__global__ __launch_bounds__(256) void k_c2(
    const u64* __restrict__ bits, const float* __restrict__ W2T,
    float* __restrict__ c2d)
{
    __shared__ u64  masksS[N1];         // 8 KB
    __shared__ u32  idxS[N1];           // 4 KB
    __shared__ float c2S[4][64][12];    // 12 KB

    const int tid  = threadIdx.x;
    const int w    = tid >> 6;      // wave = j-segment
    const int lane = tid & 63;      // = timestep in phase 2
    const int b    = blockIdx.x;

    const u64* row = bits + (size_t)b * N1;
    const int base_j = w << 8;

    // ---- phase 1: 4 loads issued upfront (independent), then ballot-compact ----
    u64 mm[4];
#pragma unroll
    for (int q = 0; q < 4; ++q) mm[q] = row[base_j + (q << 6) + lane];

    int nact = 0;
#pragma unroll
    for (int q = 0; q < 4; ++q) {
        u64 ball = __ballot(mm[q] != 0ULL);
        int pos = nact + __popcll(ball & ((1ULL << lane) - 1ULL));
        if (mm[q] != 0ULL) { masksS[base_j + pos] = mm[q]; idxS[base_j + pos] = base_j + (q << 6) + lane; }
        nact += __popcll(ball);
    }
    // zero-pad to multiple of 4 (mask=0 entries are exact no-ops: acc + 0*w == acc)
    const int npad = (nact + 3) & ~3;
    if (lane < npad - nact) { masksS[base_j + nact + lane] = 0ULL; idxS[base_j + nact + lane] = 0u; }

    // ---- phase 2: dense accumulation; lane = t; unroll 4 ----
    float acc[10];
#pragma unroll
    for (int i = 0; i < 10; ++i) acc[i] = 0.f;

    for (int a = 0; a < npad; a += 4) {
        u64 m[4]; u32 j[4];
#pragma unroll
        for (int q = 0; q < 4; ++q) {
            m[q] = masksS[base_j + a + q];
            j[q] = idxS[base_j + a + q];
        }
#pragma unroll
        for (int q = 0; q < 4; ++q) {
            float sf = (float)((m[q] >> lane) & 1ULL);
            const float* wr = W2T + j[q] * 12;       // uniform vector addr -> broadcast
            float4 w0 = *(const float4*)(wr);
            float4 w1 = *(const float4*)(wr + 4);
            float2 w2 = *(const float2*)(wr + 8);
            acc[0] = fmaf(sf, w0.x, acc[0]); acc[1] = fmaf(sf, w0.y, acc[1]);
            acc[2] = fmaf(sf, w0.z, acc[2]); acc[3] = fmaf(sf, w0.w, acc[3]);
            acc[4] = fmaf(sf, w1.x, acc[4]); acc[5] = fmaf(sf, w1.y, acc[5]);
            acc[6] = fmaf(sf, w1.z, acc[6]); acc[7] = fmaf(sf, w1.w, acc[7]);
            acc[8] = fmaf(sf, w2.x, acc[8]); acc[9] = fmaf(sf, w2.y, acc[9]);
        }
    }

#pragma unroll
    for (int i = 0; i < 10; ++i) c2S[w][lane][i] = acc[i];
    __syncthreads();

    // ---- reduce 4 partials, store dense c2d[b][t][i] (coalesced 2560B) ----
    for (int idx = tid; idx < 64 * 10; idx += 256) {
        int t = idx / 10, i = idx % 10;
        c2d[(size_t)b * 640 + idx] = ((c2S[0][t][i] + c2S[1][t][i]) + c2S[2][t][i]) + c2S[3][t][i];
    }
}

// ---------------- K3: LIF-2 over all (b,i) pairs in parallel, coalesced out writes ----------------
// 20480 threads; thread p=(b,i): 64-step recurrence in registers, 8-deep load prefetch.
__global__ __launch_bounds__(256) void k_out(
    const float* __restrict__ c2d, float* __restrict__ out)
{
    const int p = blockIdx.x * 256 + threadIdx.x;    // 0..20479
    const int b = p / 10, i = p % 10;
    const float* src = c2d + (size_t)b * 640 + i;

    float v2 = 0.f;
    for (int tb = 0; tb < 64; tb += 8) {
        float cc[8];
#pragma unroll
        for (int q = 0; q < 8; ++q) cc[q] = src[(tb + q) * 10];   // 8 loads in flight
#pragma unroll
        for (int q = 0; q < 8; ++q) {
            v2 += (cc[q] - v2) * 0.5f;
            bool s = v2 >= 1.0f;
            out[(size_t)(tb + q) * (NB * N2) + p] = s ? 1.f : 0.f; // coalesced per t
            v2 = s ? 0.f : v2;
        }
    }
}

extern "C" void kernel_launch(void* const* d_in, const int* in_sizes, int n_in,
                              void* d_out, int out_size, void* d_ws, size_t ws_size,
                              hipStream_t stream) {
    const float* X  = (const float*)d_in[0];   // [2048, 784]
    const float* W1 = (const float*)d_in[1];   // [1024, 784]
    const float* W2 = (const float*)d_in[2];   // [10, 1024]
    float* out = (float*)d_out;                // [64, 2048, 10]

    char* ws = (char*)d_ws;
    u64*   bits = (u64*)ws;                                   // 16 MiB
    float* W2T  = (float*)(ws + (size_t)NB * N1 * 8);         // 48 KiB
    float* Xt   = (float*)(ws + (size_t)NB * N1 * 8 + 65536); // 6.27 MiB
    float* W1t  = Xt + (size_t)KDIM * NB;                     // 3.14 MiB
    float* c2d  = W1t + (size_t)KDIM * N1;                    // 2048*640*4 = 5.24 MiB

    k_w2t<<<dim3((N1 + 255) / 256), dim3(256), 0, stream>>>(W2, W2T);
    k_transpose2<<<dim3(2400), dim3(256), 0, stream>>>(X, Xt, W1, W1t);

    dim3 g1(N1 / 64, NB / 64);   // (16, 32)
    k_gemm_lif1<<<g1, dim3(256), 0, stream>>>(Xt, W1t, bits);

    k_c2<<<dim3(NB), dim3(256), 0, stream>>>(bits, W2T, c2d);
    k_out<<<dim3(20480 / 256), dim3(256), 0, stream>>>(c2d, out);
}